// Round 6
// baseline (171.919 us; speedup 1.0000x reference)
//
#include <hip/hip_runtime.h>
#include <stdint.h>

// out = conv3x3_zeropad(s, W_eff), s = 3x3 reflect-pad box sum of x (B=16,C=64,H=W=128)
// R6: boxsumT 512x256 (4-row strips, paired flush); conv waves = 2 rows x 64 px
// (halves per-wave Wt2 re-reads, doubles MFMA per prefetch window), 128-thr blocks.

#define THETA 0.7f

typedef __attribute__((ext_vector_type(8))) short bf16x8;
typedef __attribute__((ext_vector_type(16))) float f32x16;

__device__ inline unsigned short f2bf(float f) {
    unsigned u = __float_as_uint(f);
    u = (u + 0x7FFFu + ((u >> 16) & 1u)) >> 16;   // RNE
    return (unsigned short)u;
}
__device__ inline void async16(const void* g, void* l) {
    __builtin_amdgcn_global_load_lds(
        (const __attribute__((address_space(1))) unsigned int*)g,
        (__attribute__((address_space(3))) unsigned int*)l, 16, 0, 0);
}

// ---------------------------------------------------------------------------
// Kernel 1: W_eff -> Wt2 bf16, lane-contiguous MFMA-A layout:
// Wt2[(tap*8 + ic*2 + mf)*512 + lane*8 + j] = W_eff[o][ch]
//   o = mf*32 + (lane&31), ch = ic*16 + (lane>>5)*8 + j
// ---------------------------------------------------------------------------
__global__ void weff_kernel(const float* __restrict__ W, unsigned short* __restrict__ Wt2) {
    int t = blockIdx.x * blockDim.x + threadIdx.x;   // 512 threads
    if (t >= 512) return;
    int o = t >> 3;
    int ch8 = t & 7;
    int c0 = ch8 * 8;
    int ic = ch8 >> 1;
    int mf = o >> 5;
    int lane = (o & 31) | ((ch8 & 1) << 5);

    float v[8][9];
    float tsum[8];
#pragma unroll
    for (int j = 0; j < 8; j++) {
        const float* w = W + ((size_t)o * 64 + c0 + j) * 9;
        float sum = 0.f;
#pragma unroll
        for (int k = 0; k < 9; k++) { v[j][k] = w[k]; sum += v[j][k]; }
        tsum[j] = sum;
    }
#pragma unroll
    for (int tap = 0; tap < 9; tap++) {
        unsigned short* dst = Wt2 + (size_t)(tap * 8 + ic * 2 + mf) * 512 + (size_t)lane * 8;
#pragma unroll
        for (int j = 0; j < 8; j++) {
            float val = v[j][tap] - ((tap == 4) ? THETA * tsum[j] : 0.f);
            dst[j] = f2bf(val);
        }
    }
}

// ---------------------------------------------------------------------------
// Kernel 2: fused box-sum + transpose. x fp32 NCHW -> s bf16 NHWC.
// Block = (b, 4-row strip), 256 thr: w4 = tid&31 (float4 of w), cg = tid>>5
// (8 channels each). Rolling vertical sums; horizontal via shfl (width 32);
// 2-row LDS transpose buffer (stride 68 -> 4-way max), paired flush.
// Grid 16*32 = 512.
// ---------------------------------------------------------------------------
__global__ __launch_bounds__(256) void boxsumT_kernel(const float* __restrict__ x,
                                                      unsigned short* __restrict__ s) {
    __shared__ unsigned short tb[2][128 * 68];   // 34816 B
    int bid = blockIdx.x;
    int b = bid >> 5;
    int h0 = (bid & 31) * 4;
    int tid = threadIdx.x;
    int w4 = tid & 31;
    int cg = tid >> 5;          // 0..7
    int c0 = cg * 8;
    const float* xp = x + ((size_t)(b * 64 + c0)) * 16384 + w4 * 4;

    float4 A[8], Bv[8], C[8];
    int hm = (h0 == 0) ? 1 : h0 - 1;
#pragma unroll
    for (int cc = 0; cc < 8; cc++) {
        A[cc]  = *(const float4*)(xp + (size_t)cc * 16384 + hm * 128);
        Bv[cc] = *(const float4*)(xp + (size_t)cc * 16384 + h0 * 128);
        C[cc]  = *(const float4*)(xp + (size_t)cc * 16384 + (h0 + 1) * 128);
    }

#pragma unroll
    for (int r = 0; r < 4; r++) {
        float4 Cn[8];
        if (r < 3) {
            int hn = h0 + 2 + r;
            if (hn > 127) hn = 126;
#pragma unroll
            for (int cc = 0; cc < 8; cc++)
                Cn[cc] = *(const float4*)(xp + (size_t)cc * 16384 + hn * 128);
        }

        unsigned short res[8][4];
#pragma unroll
        for (int cc = 0; cc < 8; cc++) {
            float4 vs;
            vs.x = A[cc].x + Bv[cc].x + C[cc].x;
            vs.y = A[cc].y + Bv[cc].y + C[cc].y;
            vs.z = A[cc].z + Bv[cc].z + C[cc].z;
            vs.w = A[cc].w + Bv[cc].w + C[cc].w;
            float L = __shfl_up(vs.w, 1, 32);
            float R = __shfl_down(vs.x, 1, 32);
            float sx = (w4 == 0) ? vs.x + 2.f * vs.y : L + vs.x + vs.y;
            float sy = vs.x + vs.y + vs.z;
            float sz = vs.y + vs.z + vs.w;
            float sw = (w4 == 31) ? 2.f * vs.z + vs.w : vs.z + vs.w + R;
            res[cc][0] = f2bf(sx);
            res[cc][1] = f2bf(sy);
            res[cc][2] = f2bf(sz);
            res[cc][3] = f2bf(sw);
        }
        unsigned short* trow = tb[r & 1];
#pragma unroll
        for (int k = 0; k < 4; k++) {
            ushort4 lo = make_ushort4(res[0][k], res[1][k], res[2][k], res[3][k]);
            ushort4 hi = make_ushort4(res[4][k], res[5][k], res[6][k], res[7][k]);
            *(ushort4*)(trow + (size_t)(w4 * 4 + k) * 68 + c0) = lo;
            *(ushort4*)(trow + (size_t)(w4 * 4 + k) * 68 + c0 + 4) = hi;
        }
#pragma unroll
        for (int cc = 0; cc < 8; cc++) { A[cc] = Bv[cc]; Bv[cc] = C[cc]; C[cc] = Cn[cc]; }

        if (r & 1) {
            __syncthreads();
            // flush rows h0+r-1 (tb[0]) and h0+r (tb[1]): 4096 ushort4 chunks
            unsigned short* sp = s + (((size_t)b * 128 + (h0 + r - 1)) * 128) * 64;
#pragma unroll
            for (int f = 0; f < 16; f++) {
                int id = f * 256 + tid;
                int rr = id >> 11;
                int rem = id & 2047;
                int w = rem >> 4;
                int c4 = (rem & 15) * 4;
                ushort4 v = *(const ushort4*)(tb[rr] + (size_t)w * 68 + c4);
                *(ushort4*)(sp + (size_t)rr * 8192 + (size_t)w * 64 + c4) = v;
            }
            __syncthreads();
        }
    }
}

// ---------------------------------------------------------------------------
// Kernel 3: implicit-GEMM conv, mfma_f32_32x32x16_bf16.
// Block = (b, 4 h-rows, 64-px w-tile), 128 thr = 2 waves; wave = 2 rows x
// 64 px x 64 o (mf=2 x rows=2 x nf=2, acc 8x f32x16). LDS staging (verified):
// 6 rows x 66 slots x 64c bf16, 16B chunks XOR-swizzled g = u ^ (slot&7).
// A from global Wt2, tap-major ping-pong prefetch. Grid 1024, 3 blocks/CU.
// ---------------------------------------------------------------------------
__global__ __launch_bounds__(128, 2) void conv_kernel(const unsigned short* __restrict__ s,
                                                      const unsigned short* __restrict__ Wt2,
                                                      float* __restrict__ out) {
    __shared__ __align__(16) unsigned short sS[6 * 66 * 64];   // 50688 B

    int bid = blockIdx.x;
    int b = bid >> 6;
    int h0 = ((bid >> 1) & 31) * 4;
    int w0 = (bid & 1) * 64;
    int tid = threadIdx.x;
    int lane = tid & 63;
    int wv = tid >> 6;          // 0..1, covers rows h0+wv*2, h0+wv*2+1
    int n32 = lane & 31;
    int q2 = lane >> 5;

    const char* sb = (const char*)s + ((size_t)b * 128) * 16384;

    int4 z = make_int4(0, 0, 0, 0);
    if (h0 == 0)
        for (int i = tid; i < 528; i += 128) *(int4*)((char*)sS + (size_t)i * 16) = z;
    if (h0 == 124)
        for (int i = tid; i < 528; i += 128) *(int4*)((char*)sS + (size_t)(5 * 528 + i) * 16) = z;

    // halo slots 0 and 65 (plain loads; per-lane divergence safe here)
    if (tid < 96) {
        int r = tid >> 4;
        int side = (tid >> 3) & 1;
        int g = tid & 7;
        int slot = side ? 65 : 0;
        int hg = h0 - 1 + r;
        int wg = w0 - 1 + slot;
        int4 v = z;
        if ((unsigned)hg < 128u && (unsigned)wg < 128u) {
            int u = g ^ (slot & 7);
            v = *(const int4*)(sb + (size_t)hg * 16384 + (size_t)wg * 128 + u * 16);
        }
        *(int4*)((char*)sS + (size_t)(r * 528 + slot * 8 + g) * 16) = v;
    }

    // interior: full-wave async, iteration-uniform row predicate (512 chunks/row)
#pragma unroll
    for (int it = 0; it < 24; it++) {
        int row = it >> 2;
        int hg = h0 - 1 + row;
        if (hg < 0 || hg > 127) continue;
        int rem = (it & 3) * 128 + tid;
        int slot = 1 + (rem >> 3);
        int g = rem & 7;
        int wg = w0 + (rem >> 3);
        int u = g ^ (slot & 7);
        async16(sb + (size_t)hg * 16384 + (size_t)wg * 128 + u * 16,
                (char*)sS + (size_t)(row * 528 + 8 + rem) * 16);
    }
    __syncthreads();

    // B LDS offsets (shorts) per (kx, ic); add (wv*2 + r + ky)*4224 + nf*2048
    int p0[3][4];
#pragma unroll
    for (int kx = 0; kx < 3; kx++)
#pragma unroll
        for (int ic = 0; ic < 4; ic++) {
            int slot = n32 + kx;
            int g = (ic * 2 + q2) ^ (slot & 7);
            p0[kx][ic] = slot * 64 + g * 8;
        }

    f32x16 acc[2][2][2];   // [mf][row][nf]
#pragma unroll
    for (int mf = 0; mf < 2; mf++)
#pragma unroll
        for (int r = 0; r < 2; r++)
#pragma unroll
            for (int nf = 0; nf < 2; nf++)
#pragma unroll
                for (int e = 0; e < 16; e++) acc[mf][r][nf][e] = 0.f;

    const unsigned short* wbase = Wt2 + (size_t)lane * 8;
    bf16x8 Af[2][8];
#pragma unroll
    for (int k = 0; k < 8; k++)
        Af[0][k] = *(const bf16x8*)(wbase + (size_t)k * 512);

#pragma unroll
    for (int tap = 0; tap < 9; tap++) {
        int cur = tap & 1;
        if (tap < 8) {
#pragma unroll
            for (int k = 0; k < 8; k++)
                Af[cur ^ 1][k] = *(const bf16x8*)(wbase + (size_t)((tap + 1) * 8 + k) * 512);
        }
        int ky = tap / 3, kx = tap % 3;
#pragma unroll
        for (int ic = 0; ic < 4; ic++) {
            const unsigned short* bp = sS + (size_t)(wv * 2 + ky) * 4224 + p0[kx][ic];
            bf16x8 b00 = *(const bf16x8*)(bp);
            bf16x8 b01 = *(const bf16x8*)(bp + 2048);
            bf16x8 b10 = *(const bf16x8*)(bp + 4224);
            bf16x8 b11 = *(const bf16x8*)(bp + 4224 + 2048);
            bf16x8 a0 = Af[cur][ic * 2 + 0];
            bf16x8 a1 = Af[cur][ic * 2 + 1];
            acc[0][0][0] = __builtin_amdgcn_mfma_f32_32x32x16_bf16(a0, b00, acc[0][0][0], 0, 0, 0);
            acc[0][0][1] = __builtin_amdgcn_mfma_f32_32x32x16_bf16(a0, b01, acc[0][0][1], 0, 0, 0);
            acc[0][1][0] = __builtin_amdgcn_mfma_f32_32x32x16_bf16(a0, b10, acc[0][1][0], 0, 0, 0);
            acc[0][1][1] = __builtin_amdgcn_mfma_f32_32x32x16_bf16(a0, b11, acc[0][1][1], 0, 0, 0);
            acc[1][0][0] = __builtin_amdgcn_mfma_f32_32x32x16_bf16(a1, b00, acc[1][0][0], 0, 0, 0);
            acc[1][0][1] = __builtin_amdgcn_mfma_f32_32x32x16_bf16(a1, b01, acc[1][0][1], 0, 0, 0);
            acc[1][1][0] = __builtin_amdgcn_mfma_f32_32x32x16_bf16(a1, b10, acc[1][1][0], 0, 0, 0);
            acc[1][1][1] = __builtin_amdgcn_mfma_f32_32x32x16_bf16(a1, b11, acc[1][1][1], 0, 0, 0);
        }
    }

    // epilogue: 32x32 C/D layout col=lane&31 (pixel), row=(e&3)+8*(e>>2)+4*q2 (o)
    float* ob = out + ((size_t)b * 64) * 16384 + (size_t)(h0 + wv * 2) * 128 + w0;
#pragma unroll
    for (int mf = 0; mf < 2; mf++)
#pragma unroll
        for (int r = 0; r < 2; r++)
#pragma unroll
            for (int nf = 0; nf < 2; nf++)
#pragma unroll
                for (int e = 0; e < 16; e++) {
                    int o = mf * 32 + (e & 3) + 8 * (e >> 2) + 4 * q2;
                    ob[(size_t)o * 16384 + (size_t)r * 128 + nf * 32 + n32] = acc[mf][r][nf][e];
                }
}

// ---------------------------------------------------------------------------
extern "C" void kernel_launch(void* const* d_in, const int* in_sizes, int n_in,
                              void* d_out, int out_size, void* d_ws, size_t ws_size,
                              hipStream_t stream) {
    const float* x = (const float*)d_in[0];   // [16][64][128][128] fp32
    const float* W = (const float*)d_in[1];   // [64][64][3][3] fp32
    float* outp = (float*)d_out;

    // ws: Wt2 bf16 (73728 B) | s bf16 NHWC (33554432 B)
    unsigned short* Wt2 = (unsigned short*)d_ws;
    unsigned short* s = (unsigned short*)((char*)d_ws + 73728);

    weff_kernel<<<2, 256, 0, stream>>>(W, Wt2);
    boxsumT_kernel<<<512, 256, 0, stream>>>(x, s);
    conv_kernel<<<1024, 128, 0, stream>>>(s, Wt2, outp);
}